// Round 1
// baseline (432.579 us; speedup 1.0000x reference)
//
#include <hip/hip_runtime.h>
#include <stdint.h>
#include <stddef.h>

typedef unsigned short u16;
typedef __attribute__((ext_vector_type(4))) unsigned short u16x4;
typedef __attribute__((ext_vector_type(8))) short bf16x8;
typedef __attribute__((ext_vector_type(4))) float f32x4;

// problem dims (fixed by setup_inputs)
#define B_   2
#define T_   2048
#define NH   16
#define NKV  8
#define HD   128

__device__ __forceinline__ u16 f2bf(float f) {
  union { float f; uint32_t u; } v; v.f = f;
  uint32_t u = v.u;
  u += 0x7FFFu + ((u >> 16) & 1u);   // round-to-nearest-even
  return (u16)(u >> 16);
}
__device__ __forceinline__ float bf2f(u16 h) {
  union { uint32_t u; float f; } v; v.u = ((uint32_t)h) << 16;
  return v.f;
}

// async global->LDS, 16B per lane. LDS dest must be linear in lane order.
__device__ __forceinline__ void gload_lds16(const void* g, void* l) {
  __builtin_amdgcn_global_load_lds(
      (__attribute__((address_space(1))) void*)g,
      (__attribute__((address_space(3))) void*)l, 16, 0, 0);
}

// ---------------- fp32 -> bf16 conversion ----------------
__global__ __launch_bounds__(256) void cvt_f32_bf16(const float* __restrict__ in,
                                                    u16* __restrict__ out, int n4) {
  int i = blockIdx.x * 256 + threadIdx.x;
  if (i >= n4) return;
  float4 v = reinterpret_cast<const float4*>(in)[i];
  u16x4 o;
  o.x = f2bf(v.x); o.y = f2bf(v.y); o.z = f2bf(v.z); o.w = f2bf(v.w);
  reinterpret_cast<u16x4*>(out)[i] = o;
}

// ---------------- GEMM: C = A[M,K] * B[N,K]^T (bf16 in, bf16/f32 out) -------
// STORE: 0 = bf16 row-major [M,N]; 1 = bf16 transposed to [B][N][T] (for V^T);
//        2 = f32 row-major [M,N]
template<int STORE>
__global__ __launch_bounds__(256) void gemm_bt(const u16* __restrict__ A,
                                               const u16* __restrict__ Bm,
                                               void* __restrict__ Cv,
                                               int M, int N, int K) {
  __shared__ u16 Alds[128 * 64];
  __shared__ u16 Blds[128 * 64];
  const int tid  = threadIdx.x;
  const int lane = tid & 63;
  const int wid  = tid >> 6;
  const int lr   = lane & 15;
  const int lg   = lane >> 4;
  const int m0 = blockIdx.y * 128;
  const int n0 = blockIdx.x * 128;
  const int wm = (wid >> 1) * 64;
  const int wn = (wid & 1) * 64;

  f32x4 acc[4][4];
#pragma unroll
  for (int i = 0; i < 4; ++i)
#pragma unroll
    for (int j = 0; j < 4; ++j) acc[i][j] = (f32x4){0.f, 0.f, 0.f, 0.f};

  const int srow = tid >> 3;   // staging: 8 x 16B chunks per 128-bf16 row
  const int sch  = tid & 7;
  const int nk = K >> 6;
  for (int kt = 0; kt < nk; ++kt) {
    const int k0 = kt << 6;
#pragma unroll
    for (int it = 0; it < 4; ++it) {
      const int row = it * 32 + srow;
      gload_lds16(A + (size_t)(m0 + row) * K + k0 + sch * 8,
                  (char*)Alds + (it * 256 + tid) * 16);
    }
#pragma unroll
    for (int it = 0; it < 4; ++it) {
      const int row = it * 32 + srow;
      gload_lds16(Bm + (size_t)(n0 + row) * K + k0 + sch * 8,
                  (char*)Blds + (it * 256 + tid) * 16);
    }
    __syncthreads();   // drains vmcnt: tiles ready

    bf16x8 af[4][2], bfr[4][2];
#pragma unroll
    for (int mt = 0; mt < 4; ++mt)
#pragma unroll
      for (int kk = 0; kk < 2; ++kk)
        af[mt][kk] = *reinterpret_cast<const bf16x8*>(
            (const char*)Alds + (wm + mt * 16 + lr) * 128 + kk * 64 + lg * 16);
#pragma unroll
    for (int nt = 0; nt < 4; ++nt)
#pragma unroll
      for (int kk = 0; kk < 2; ++kk)
        bfr[nt][kk] = *reinterpret_cast<const bf16x8*>(
            (const char*)Blds + (wn + nt * 16 + lr) * 128 + kk * 64 + lg * 16);
#pragma unroll
    for (int mt = 0; mt < 4; ++mt)
#pragma unroll
      for (int nt = 0; nt < 4; ++nt)
#pragma unroll
        for (int kk = 0; kk < 2; ++kk)
          acc[mt][nt] = __builtin_amdgcn_mfma_f32_16x16x32_bf16(
              af[mt][kk], bfr[nt][kk], acc[mt][nt], 0, 0, 0);
    __syncthreads();   // all reads done before next-stage overwrite
  }

  if (STORE == 0) {
    u16* C = (u16*)Cv;
#pragma unroll
    for (int mt = 0; mt < 4; ++mt) {
      const int row = m0 + wm + mt * 16 + lg * 4;
#pragma unroll
      for (int nt = 0; nt < 4; ++nt) {
        const int col = n0 + wn + nt * 16 + lr;
#pragma unroll
        for (int r = 0; r < 4; ++r)
          C[(size_t)(row + r) * N + col] = f2bf(acc[mt][nt][r]);
      }
    }
  } else if (STORE == 2) {
    float* C = (float*)Cv;
#pragma unroll
    for (int mt = 0; mt < 4; ++mt) {
      const int row = m0 + wm + mt * 16 + lg * 4;
#pragma unroll
      for (int nt = 0; nt < 4; ++nt) {
        const int col = n0 + wn + nt * 16 + lr;
#pragma unroll
        for (int r = 0; r < 4; ++r)
          C[(size_t)(row + r) * N + col] = acc[mt][nt][r];
      }
    }
  } else {  // STORE == 1: out[b][col][t], t = row % T_
    u16* C = (u16*)Cv;
#pragma unroll
    for (int mt = 0; mt < 4; ++mt) {
      const int row = m0 + wm + mt * 16 + lg * 4;
      const int b = row >> 11;           // / T_
      const int t = row & (T_ - 1);
#pragma unroll
      for (int nt = 0; nt < 4; ++nt) {
        const int col = n0 + wn + nt * 16 + lr;
        u16x4 v;
        v.x = f2bf(acc[mt][nt][0]); v.y = f2bf(acc[mt][nt][1]);
        v.z = f2bf(acc[mt][nt][2]); v.w = f2bf(acc[mt][nt][3]);
        *reinterpret_cast<u16x4*>(C + ((size_t)b * N + col) * T_ + t) = v;
      }
    }
  }
}

// ---------------- per-head RMSNorm + RoPE on Q and K (in-place, bf16) -------
__global__ __launch_bounds__(256) void rms_rope(u16* __restrict__ Q, u16* __restrict__ Kb,
                                                const float* __restrict__ cosT,
                                                const float* __restrict__ sinT,
                                                const int* __restrict__ pos,
                                                const float* __restrict__ qw,
                                                const float* __restrict__ kw) {
  const int wave = blockIdx.x * 4 + (threadIdx.x >> 6);
  const int lane = threadIdx.x & 63;
  const int bt = wave & (B_ * T_ - 1);   // 4096 = 2^12
  const int hh = wave >> 12;             // 0..23: 0-15 Q heads, 16-23 K heads
  u16* ptr;
  const float* w;
  if (hh < NH) { ptr = Q + (size_t)bt * (NH * HD) + hh * HD; w = qw; }
  else         { ptr = Kb + (size_t)bt * (NKV * HD) + (hh - NH) * HD; w = kw; }
  const int p = pos[bt];

  float e0 = bf2f(ptr[lane]);
  float e1 = bf2f(ptr[lane + 64]);
  float ss = e0 * e0 + e1 * e1;
#pragma unroll
  for (int off = 1; off < 64; off <<= 1) ss += __shfl_xor(ss, off, 64);
  const float r = rsqrtf(ss * (1.0f / 128.0f) + 1e-6f);
  const float n0 = e0 * r * w[lane];
  const float n1 = e1 * r * w[lane + 64];
  const float c0 = cosT[(size_t)p * HD + lane], c1 = cosT[(size_t)p * HD + lane + 64];
  const float s0 = sinT[(size_t)p * HD + lane], s1 = sinT[(size_t)p * HD + lane + 64];
  // rotate_half: out[i] = x[i]*cos[i] - x[i+64]*sin[i];  out[i+64] = x[i+64]*cos[i+64] + x[i]*sin[i+64]
  ptr[lane]      = f2bf(n0 * c0 - n1 * s0);
  ptr[lane + 64] = f2bf(n1 * c1 + n0 * s1);
}

// ---------------- causal flash attention (GQA), bf16 MFMA -------------------
// grid: B_*NH*(T_/64) blocks, 256 threads (4 waves x 16 q-rows).
__global__ __launch_bounds__(256) void flash_attn(const u16* __restrict__ Qw,
                                                  const u16* __restrict__ Kw,
                                                  const u16* __restrict__ VTw,
                                                  u16* __restrict__ Ow) {
  __shared__ u16 Klds[64 * 128];       // [kv][d], XOR-swizzled within row
  __shared__ u16 Vlds[128 * 64];       // [d][kv], XOR-swizzled within row
  __shared__ u16 Plds[4][16 * 80];     // per-wave P, rows padded to 80 elems

  const int tid  = threadIdx.x;
  const int lane = tid & 63;
  const int wid  = tid >> 6;
  const int lr   = lane & 15;
  const int lg   = lane >> 4;
  const int blk = blockIdx.x;
  const int qt = blk & 31;             // T_/64 = 32
  const int h  = (blk >> 5) & (NH - 1);
  const int b  = blk >> 9;
  const int kvh = h >> 1;              // groups = NH/NKV = 2
  const int q0w = qt * 64 + wid * 16;

  bf16x8 qf[4];
  {
    const u16* qp = Qw + ((size_t)(b * T_) + q0w + lr) * (NH * HD) + h * HD + lg * 8;
#pragma unroll
    for (int kk = 0; kk < 4; ++kk) qf[kk] = *reinterpret_cast<const bf16x8*>(qp + kk * 32);
  }
  f32x4 o[8];
#pragma unroll
  for (int dt = 0; dt < 8; ++dt) o[dt] = (f32x4){0.f, 0.f, 0.f, 0.f};
  float m[4]    = {-1e30f, -1e30f, -1e30f, -1e30f};
  float lsum[4] = {0.f, 0.f, 0.f, 0.f};
  const float scale = 0.08838834764831845f;  // 1/sqrt(128)

  const int nkt = qt + 1;
  for (int kt = 0; kt < nkt; ++kt) {
    __syncthreads();   // previous tile fully consumed
    {  // stage K tile: 64 rows x 128 bf16 (256B/row, 16 chunks)
      const int row = tid >> 4, ch = tid & 15;
#pragma unroll
      for (int it = 0; it < 4; ++it) {
        const int rr = it * 16 + row;
        const int scol = ((ch * 16) ^ ((rr & 7) << 4)) >> 1;  // pre-swizzled source col (elems)
        gload_lds16(Kw + ((size_t)(b * T_) + kt * 64 + rr) * (NKV * HD) + kvh * HD + scol,
                    (char*)Klds + (it * 256 + tid) * 16);
      }
    }
    {  // stage V^T tile: 128 rows x 64 bf16 (128B/row, 8 chunks)
      const int row = tid >> 3, ch = tid & 7;
#pragma unroll
      for (int it = 0; it < 4; ++it) {
        const int rr = it * 32 + row;
        const int scol = ((ch * 16) ^ ((rr & 7) << 4)) >> 1;
        gload_lds16(VTw + ((size_t)(b * NKV * HD) + kvh * HD + rr) * T_ + kt * 64 + scol,
                    (char*)Vlds + (it * 256 + tid) * 16);
      }
    }
    __syncthreads();   // tiles ready (vmcnt drained)

    // S = Q K^T
    f32x4 s[4];
#pragma unroll
    for (int nt = 0; nt < 4; ++nt) {
      s[nt] = (f32x4){0.f, 0.f, 0.f, 0.f};
#pragma unroll
      for (int kk = 0; kk < 4; ++kk) {
        const int row = nt * 16 + lr;
        const int kb = (kk * 64 + lg * 16) ^ ((row & 7) << 4);
        const bf16x8 kf = *reinterpret_cast<const bf16x8*>((const char*)Klds + row * 256 + kb);
        s[nt] = __builtin_amdgcn_mfma_f32_16x16x32_bf16(qf[kk], kf, s[nt], 0, 0, 0);
      }
    }

    // scale + causal mask + online softmax (rows lg*4+r, cols nt*16+lr)
    const bool diag = (kt == qt);
    float alpha[4];
#pragma unroll
    for (int r = 0; r < 4; ++r) {
      const int qg = q0w + lg * 4 + r;
      float rm = -1e30f;
#pragma unroll
      for (int nt = 0; nt < 4; ++nt) {
        float sv = s[nt][r] * scale;
        if (diag && (kt * 64 + nt * 16 + lr) > qg) sv = -1e30f;
        s[nt][r] = sv;
        rm = fmaxf(rm, sv);
      }
#pragma unroll
      for (int off = 1; off < 16; off <<= 1) rm = fmaxf(rm, __shfl_xor(rm, off, 64));
      const float mn = fmaxf(m[r], rm);
      alpha[r] = __expf(m[r] - mn);
      float rs = 0.f;
#pragma unroll
      for (int nt = 0; nt < 4; ++nt) {
        const float p = __expf(s[nt][r] - mn);
        s[nt][r] = p;
        rs += p;
      }
#pragma unroll
      for (int off = 1; off < 16; off <<= 1) rs += __shfl_xor(rs, off, 64);
      lsum[r] = lsum[r] * alpha[r] + rs;
      m[r] = mn;
    }
#pragma unroll
    for (int dt = 0; dt < 8; ++dt) {
      f32x4 ov = o[dt];
      ov[0] *= alpha[0]; ov[1] *= alpha[1]; ov[2] *= alpha[2]; ov[3] *= alpha[3];
      o[dt] = ov;
    }

    // P -> per-wave LDS (bf16), then PV
    u16* pb = &Plds[wid][0];
#pragma unroll
    for (int r = 0; r < 4; ++r)
#pragma unroll
      for (int nt = 0; nt < 4; ++nt)
        pb[(lg * 4 + r) * 80 + nt * 16 + lr] = f2bf(s[nt][r]);

#pragma unroll
    for (int kb2 = 0; kb2 < 2; ++kb2) {
      const bf16x8 pa = *reinterpret_cast<const bf16x8*>(
          (const char*)pb + lr * 160 + kb2 * 64 + lg * 16);
#pragma unroll
      for (int dt = 0; dt < 8; ++dt) {
        const int row = dt * 16 + lr;
        const int cb = (kb2 * 64 + lg * 16) ^ ((row & 7) << 4);
        const bf16x8 vf = *reinterpret_cast<const bf16x8*>((const char*)Vlds + row * 128 + cb);
        o[dt] = __builtin_amdgcn_mfma_f32_16x16x32_bf16(pa, vf, o[dt], 0, 0, 0);
      }
    }
  }

  float inv[4];
#pragma unroll
  for (int r = 0; r < 4; ++r) inv[r] = 1.0f / lsum[r];
#pragma unroll
  for (int dt = 0; dt < 8; ++dt)
#pragma unroll
    for (int r = 0; r < 4; ++r) {
      const int qg = q0w + lg * 4 + r;
      Ow[((size_t)(b * T_) + qg) * (NH * HD) + h * HD + dt * 16 + lr] = f2bf(o[dt][r] * inv[r]);
    }
}

// ---------------- host launch ----------------
extern "C" void kernel_launch(void* const* d_in, const int* in_sizes, int n_in,
                              void* d_out, int out_size, void* d_ws, size_t ws_size,
                              hipStream_t stream) {
  (void)in_sizes; (void)n_in; (void)out_size; (void)ws_size;
  const float* x    = (const float*)d_in[0];
  const float* cosT = (const float*)d_in[1];
  const float* sinT = (const float*)d_in[2];
  const int*   pos  = (const int*)d_in[3];
  const float* Wq   = (const float*)d_in[4];
  const float* Wk   = (const float*)d_in[5];
  const float* Wv   = (const float*)d_in[6];
  const float* Wo   = (const float*)d_in[7];
  const float* qw   = (const float*)d_in[8];
  const float* kw   = (const float*)d_in[9];
  float* out = (float*)d_out;

  char* ws = (char*)d_ws;
  u16* xb   = (u16*)(ws + 0);          // 16.78 MB  [4096][2048]
  u16* Wqb  = (u16*)(ws + 16777216);   //  8.39 MB  [2048][2048]
  u16* Wkb  = (u16*)(ws + 25165824);   //  4.19 MB  [1024][2048]
  u16* Wvb  = (u16*)(ws + 29360128);   //  4.19 MB  [1024][2048]
  u16* Wob  = (u16*)(ws + 33554432);   //  8.39 MB  [2048][2048]
  u16* Qws  = (u16*)(ws + 41943040);   // 16.78 MB  [4096][16*128]
  u16* Kws  = (u16*)(ws + 58720256);   //  8.39 MB  [4096][8*128]
  u16* VTws = (u16*)(ws + 67108864);   //  8.39 MB  [2][1024][2048]
  u16* Aws  = (u16*)(ws + 75497472);   // 16.78 MB  [4096][2048]
  // total 92,274,688 B

  cvt_f32_bf16<<<8192, 256, 0, stream>>>(x,  xb,  2097152);
  cvt_f32_bf16<<<4096, 256, 0, stream>>>(Wq, Wqb, 1048576);
  cvt_f32_bf16<<<2048, 256, 0, stream>>>(Wk, Wkb, 524288);
  cvt_f32_bf16<<<2048, 256, 0, stream>>>(Wv, Wvb, 524288);
  cvt_f32_bf16<<<4096, 256, 0, stream>>>(Wo, Wob, 1048576);

  gemm_bt<0><<<dim3(16, 32), 256, 0, stream>>>(xb, Wqb, Qws, 4096, 2048, 2048);
  gemm_bt<0><<<dim3(8, 32),  256, 0, stream>>>(xb, Wkb, Kws, 4096, 1024, 2048);
  gemm_bt<1><<<dim3(8, 32),  256, 0, stream>>>(xb, Wvb, VTws, 4096, 1024, 2048);

  rms_rope<<<24576, 256, 0, stream>>>(Qws, Kws, cosT, sinT, pos, qw, kw);

  flash_attn<<<1024, 256, 0, stream>>>(Qws, Kws, VTws, Aws);

  gemm_bt<2><<<dim3(16, 32), 256, 0, stream>>>(Aws, Wob, out, 4096, 2048, 2048);
}

// Round 3
// 319.929 us; speedup vs baseline: 1.3521x; 1.3521x over previous
//
#include <hip/hip_runtime.h>
#include <stdint.h>
#include <stddef.h>

typedef unsigned short u16;
typedef __attribute__((ext_vector_type(4))) unsigned short u16x4;
typedef __attribute__((ext_vector_type(8))) short bf16x8;
typedef __attribute__((ext_vector_type(4))) float f32x4;
typedef __attribute__((ext_vector_type(16))) float f32x16;

// problem dims (fixed by setup_inputs)
#define B_   2
#define T_   2048
#define NH   16
#define NKV  8
#define HD   128

__device__ __forceinline__ u16 f2bf(float f) {
  union { float f; uint32_t u; } v; v.f = f;
  uint32_t u = v.u;
  u += 0x7FFFu + ((u >> 16) & 1u);   // round-to-nearest-even
  return (u16)(u >> 16);
}
__device__ __forceinline__ float bf2f(u16 h) {
  union { uint32_t u; float f; } v; v.u = ((uint32_t)h) << 16;
  return v.f;
}
__device__ __forceinline__ uint32_t cvt_pk_bf16(float lo, float hi) {
  uint32_t r;
  asm("v_cvt_pk_bf16_f32 %0, %1, %2" : "=v"(r) : "v"(lo), "v"(hi));
  return r;
}

// async global->LDS, 16B per lane. LDS dest must be linear in lane order.
__device__ __forceinline__ void gload_lds16(const void* g, void* l) {
  __builtin_amdgcn_global_load_lds(
      (__attribute__((address_space(1))) void*)g,
      (__attribute__((address_space(3))) void*)l, 16, 0, 0);
}

// ---------------- fp32 -> bf16 conversion ----------------
__global__ __launch_bounds__(256) void cvt_f32_bf16(const float* __restrict__ in,
                                                    u16* __restrict__ out, int n4) {
  int i = blockIdx.x * 256 + threadIdx.x;
  if (i >= n4) return;
  float4 v = reinterpret_cast<const float4*>(in)[i];
  u16x4 o;
  o.x = f2bf(v.x); o.y = f2bf(v.y); o.z = f2bf(v.z); o.w = f2bf(v.w);
  reinterpret_cast<u16x4*>(out)[i] = o;
}

// ---------------- GEMM: C = A[M,K] * B[N,K]^T (bf16 in, bf16/f32 out) -------
template<int STORE>
__global__ __launch_bounds__(256) void gemm_bt(const u16* __restrict__ A,
                                               const u16* __restrict__ Bm,
                                               void* __restrict__ Cv,
                                               int M, int N, int K) {
  __shared__ u16 Alds[128 * 64];
  __shared__ u16 Blds[128 * 64];
  const int tid  = threadIdx.x;
  const int lane = tid & 63;
  const int wid  = tid >> 6;
  const int lr   = lane & 15;
  const int lg   = lane >> 4;
  const int m0 = blockIdx.y * 128;
  const int n0 = blockIdx.x * 128;
  const int wm = (wid >> 1) * 64;
  const int wn = (wid & 1) * 64;

  f32x4 acc[4][4];
#pragma unroll
  for (int i = 0; i < 4; ++i)
#pragma unroll
    for (int j = 0; j < 4; ++j) acc[i][j] = (f32x4){0.f, 0.f, 0.f, 0.f};

  const int srow = tid >> 3;
  const int sch  = tid & 7;
  const int nk = K >> 6;
  for (int kt = 0; kt < nk; ++kt) {
    const int k0 = kt << 6;
#pragma unroll
    for (int it = 0; it < 4; ++it) {
      const int row = it * 32 + srow;
      gload_lds16(A + (size_t)(m0 + row) * K + k0 + sch * 8,
                  (char*)Alds + (it * 256 + tid) * 16);
    }
#pragma unroll
    for (int it = 0; it < 4; ++it) {
      const int row = it * 32 + srow;
      gload_lds16(Bm + (size_t)(n0 + row) * K + k0 + sch * 8,
                  (char*)Blds + (it * 256 + tid) * 16);
    }
    __syncthreads();

    bf16x8 af[4][2], bfr[4][2];
#pragma unroll
    for (int mt = 0; mt < 4; ++mt)
#pragma unroll
      for (int kk = 0; kk < 2; ++kk)
        af[mt][kk] = *reinterpret_cast<const bf16x8*>(
            (const char*)Alds + (wm + mt * 16 + lr) * 128 + kk * 64 + lg * 16);
#pragma unroll
    for (int nt = 0; nt < 4; ++nt)
#pragma unroll
      for (int kk = 0; kk < 2; ++kk)
        bfr[nt][kk] = *reinterpret_cast<const bf16x8*>(
            (const char*)Blds + (wn + nt * 16 + lr) * 128 + kk * 64 + lg * 16);
#pragma unroll
    for (int mt = 0; mt < 4; ++mt)
#pragma unroll
      for (int nt = 0; nt < 4; ++nt)
#pragma unroll
        for (int kk = 0; kk < 2; ++kk)
          acc[mt][nt] = __builtin_amdgcn_mfma_f32_16x16x32_bf16(
              af[mt][kk], bfr[nt][kk], acc[mt][nt], 0, 0, 0);
    __syncthreads();
  }

  if (STORE == 0) {
    u16* C = (u16*)Cv;
#pragma unroll
    for (int mt = 0; mt < 4; ++mt) {
      const int row = m0 + wm + mt * 16 + lg * 4;
#pragma unroll
      for (int nt = 0; nt < 4; ++nt) {
        const int col = n0 + wn + nt * 16 + lr;
#pragma unroll
        for (int r = 0; r < 4; ++r)
          C[(size_t)(row + r) * N + col] = f2bf(acc[mt][nt][r]);
      }
    }
  } else if (STORE == 2) {
    float* C = (float*)Cv;
#pragma unroll
    for (int mt = 0; mt < 4; ++mt) {
      const int row = m0 + wm + mt * 16 + lg * 4;
#pragma unroll
      for (int nt = 0; nt < 4; ++nt) {
        const int col = n0 + wn + nt * 16 + lr;
#pragma unroll
        for (int r = 0; r < 4; ++r)
          C[(size_t)(row + r) * N + col] = acc[mt][nt][r];
      }
    }
  } else {  // STORE == 1: out[b][col][t]
    u16* C = (u16*)Cv;
#pragma unroll
    for (int mt = 0; mt < 4; ++mt) {
      const int row = m0 + wm + mt * 16 + lg * 4;
      const int b = row >> 11;
      const int t = row & (T_ - 1);
#pragma unroll
      for (int nt = 0; nt < 4; ++nt) {
        const int col = n0 + wn + nt * 16 + lr;
        u16x4 v;
        v.x = f2bf(acc[mt][nt][0]); v.y = f2bf(acc[mt][nt][1]);
        v.z = f2bf(acc[mt][nt][2]); v.w = f2bf(acc[mt][nt][3]);
        *reinterpret_cast<u16x4*>(C + ((size_t)b * N + col) * T_ + t) = v;
      }
    }
  }
}

// ---------------- per-head RMSNorm + RoPE on Q and K (in-place, bf16) -------
__global__ __launch_bounds__(256) void rms_rope(u16* __restrict__ Q, u16* __restrict__ Kb,
                                                const float* __restrict__ cosT,
                                                const float* __restrict__ sinT,
                                                const int* __restrict__ pos,
                                                const float* __restrict__ qw,
                                                const float* __restrict__ kw) {
  const int wave = blockIdx.x * 4 + (threadIdx.x >> 6);
  const int lane = threadIdx.x & 63;
  const int bt = wave & (B_ * T_ - 1);
  const int hh = wave >> 12;
  u16* ptr;
  const float* w;
  if (hh < NH) { ptr = Q + (size_t)bt * (NH * HD) + hh * HD; w = qw; }
  else         { ptr = Kb + (size_t)bt * (NKV * HD) + (hh - NH) * HD; w = kw; }
  const int p = pos[bt];

  float e0 = bf2f(ptr[lane]);
  float e1 = bf2f(ptr[lane + 64]);
  float ss = e0 * e0 + e1 * e1;
#pragma unroll
  for (int off = 1; off < 64; off <<= 1) ss += __shfl_xor(ss, off, 64);
  const float r = rsqrtf(ss * (1.0f / 128.0f) + 1e-6f);
  const float n0 = e0 * r * w[lane];
  const float n1 = e1 * r * w[lane + 64];
  const float c0 = cosT[(size_t)p * HD + lane], c1 = cosT[(size_t)p * HD + lane + 64];
  const float s0 = sinT[(size_t)p * HD + lane], s1 = sinT[(size_t)p * HD + lane + 64];
  ptr[lane]      = f2bf(n0 * c0 - n1 * s0);
  ptr[lane + 64] = f2bf(n1 * c1 + n0 * s1);
}

// ---------------- causal flash attention, swapped-QK^T 32x32 structure ------
// 4 waves x 32 q-rows = 128 q/block; KVBLK=64; grid 512 blocks.
__global__ __launch_bounds__(256, 2) void flash_attn2(const u16* __restrict__ Qw,
                                                      const u16* __restrict__ Kw,
                                                      const u16* __restrict__ VTw,
                                                      u16* __restrict__ Ow) {
  __shared__ __align__(16) char smem[34816];
  u16* Kb = (u16*)smem;              // [64 kv][128 d], 256B rows, XOR-swizzled
  u16* Vb = (u16*)(smem + 16384);    // [128 d][64 kv], 128B rows, XOR-swizzled

  const int tid  = threadIdx.x;
  const int lane = tid & 63;
  const int wid  = tid >> 6;
  const int rl   = lane & 31;
  const int hi   = lane >> 5;
  const int blk  = blockIdx.x;
  // paired-qt mapping: first 256 blocks qt=15..8, last 256 qt=0..7
  const int qtr = blk >> 5;
  const int qt  = (blk < 256) ? (15 - qtr) : (qtr - 8);
  const int bh  = blk & 31;
  const int b   = bh >> 4, h = bh & 15, kvh = h >> 1;
  const int q0w = qt * 128 + wid * 32;
  const int qg  = q0w + rl;              // this lane's q row
  const int swz = (rl & 7) << 4;

  // Q fragments (B-operand): lane holds Q[qg][16*kd + 8*hi + 0..7]
  bf16x8 qf[8];
  {
    const u16* qp = Qw + ((size_t)(b * T_) + qg) * (NH * HD) + h * HD + hi * 8;
#pragma unroll
    for (int kd = 0; kd < 8; ++kd) qf[kd] = *reinterpret_cast<const bf16x8*>(qp + kd * 16);
  }

  f32x16 ot[4];   // O^T accum: [dt] rows d=dt*32+crow, col q=rl
#pragma unroll
  for (int dt = 0; dt < 4; ++dt)
#pragma unroll
    for (int r = 0; r < 16; ++r) ot[dt][r] = 0.f;
  float m = -1e30f, lsum = 0.f;
  const float scale = 0.08838834764831845f;

  const int nkt = 2 * qt + 2;
  for (int kt = 0; kt < nkt; ++kt) {
    __syncthreads();   // previous tile fully consumed
    {  // stage K tile: 64 rows x 256B (16 chunks/row)
      const int row = tid >> 4, ch = tid & 15;
#pragma unroll
      for (int it = 0; it < 4; ++it) {
        const int rr = it * 16 + row;
        const int scol = ((ch * 16) ^ ((rr & 7) << 4)) >> 1;
        gload_lds16(Kw + ((size_t)(b * T_) + kt * 64 + rr) * (NKV * HD) + kvh * HD + scol,
                    (char*)Kb + (it * 256 + tid) * 16);
      }
    }
    {  // stage V^T tile: 128 rows x 128B (8 chunks/row)
      const int row = tid >> 3, ch = tid & 7;
#pragma unroll
      for (int it = 0; it < 4; ++it) {
        const int rr = it * 32 + row;
        const int scol = ((ch * 16) ^ ((rr & 7) << 4)) >> 1;
        gload_lds16(VTw + ((size_t)((b * NKV + kvh) * HD) + rr) * T_ + kt * 64 + scol,
                    (char*)Vb + (it * 256 + tid) * 16);
      }
    }
    __syncthreads();   // tiles ready

    if (64 * kt <= q0w + 31) {   // wave has at least one unmasked kv
      // S^T = K · Q^T : two 32x32 outputs (kv chunks), K-dim = d
      f32x16 s0, s1;
#pragma unroll
      for (int r = 0; r < 16; ++r) { s0[r] = 0.f; s1[r] = 0.f; }
      __builtin_amdgcn_s_setprio(1);
#pragma unroll
      for (int kd = 0; kd < 8; ++kd) {
        const int cb = (kd * 32 + hi * 16) ^ swz;
        const bf16x8 k0 = *reinterpret_cast<const bf16x8*>((const char*)Kb + rl * 256 + cb);
        const bf16x8 k1 = *reinterpret_cast<const bf16x8*>((const char*)Kb + (32 + rl) * 256 + cb);
        s0 = __builtin_amdgcn_mfma_f32_32x32x16_bf16(k0, qf[kd], s0, 0, 0, 0);
        s1 = __builtin_amdgcn_mfma_f32_32x32x16_bf16(k1, qf[kd], s1, 0, 0, 0);
      }
      __builtin_amdgcn_s_setprio(0);

      // scale + causal mask + lane-local online softmax
      const int kv0 = kt * 64;
      const bool maskT = (kv0 + 63 > q0w);
      float rm = -1e30f;
#pragma unroll
      for (int r = 0; r < 16; ++r) {
        const int cr = (r & 3) + 8 * (r >> 2) + 4 * hi;
        float a = s0[r] * scale, c = s1[r] * scale;
        if (maskT) {
          if (kv0 + cr > qg)      a = -1e30f;
          if (kv0 + 32 + cr > qg) c = -1e30f;
        }
        s0[r] = a; s1[r] = c;
        rm = fmaxf(rm, fmaxf(a, c));
      }
      rm = fmaxf(rm, __shfl_xor(rm, 32));
      const float mn = fmaxf(m, rm);
      const float al = __expf(m - mn);
      m = mn;
      float rs = 0.f;
#pragma unroll
      for (int r = 0; r < 16; ++r) {
        const float p0 = __expf(s0[r] - mn);
        const float p1 = __expf(s1[r] - mn);
        s0[r] = p0; s1[r] = p1;
        rs += p0 + p1;
      }
      rs += __shfl_xor(rs, 32);
      lsum = lsum * al + rs;
#pragma unroll
      for (int dt = 0; dt < 4; ++dt)
#pragma unroll
        for (int r = 0; r < 16; ++r) ot[dt][r] *= al;

      // pack P -> bf16 B-operand frags via cvt_pk + permlane32_swap.
      // swap(X,Y): X_new = {X_lo; Y_lo-from-partner} = w0/w1,
      //            Y_new = {X_hi-from-partner; Y_hi} = w2/w3.
      bf16x8 pf[2][2];
#pragma unroll
      for (int ks = 0; ks < 2; ++ks) {
        {
          uint32_t X0 = cvt_pk_bf16(s0[8 * ks + 0], s0[8 * ks + 1]);
          uint32_t X1 = cvt_pk_bf16(s0[8 * ks + 2], s0[8 * ks + 3]);
          uint32_t Y0 = cvt_pk_bf16(s0[8 * ks + 4], s0[8 * ks + 5]);
          uint32_t Y1 = cvt_pk_bf16(s0[8 * ks + 6], s0[8 * ks + 7]);
          asm volatile("v_permlane32_swap_b32 %0, %1" : "+v"(X0), "+v"(Y0));
          asm volatile("v_permlane32_swap_b32 %0, %1" : "+v"(X1), "+v"(Y1));
          union { uint32_t w[4]; bf16x8 v; } u;
          u.w[0] = X0; u.w[1] = X1; u.w[2] = Y0; u.w[3] = Y1;
          pf[0][ks] = u.v;
        }
        {
          uint32_t X0 = cvt_pk_bf16(s1[8 * ks + 0], s1[8 * ks + 1]);
          uint32_t X1 = cvt_pk_bf16(s1[8 * ks + 2], s1[8 * ks + 3]);
          uint32_t Y0 = cvt_pk_bf16(s1[8 * ks + 4], s1[8 * ks + 5]);
          uint32_t Y1 = cvt_pk_bf16(s1[8 * ks + 6], s1[8 * ks + 7]);
          asm volatile("v_permlane32_swap_b32 %0, %1" : "+v"(X0), "+v"(Y0));
          asm volatile("v_permlane32_swap_b32 %0, %1" : "+v"(X1), "+v"(Y1));
          union { uint32_t w[4]; bf16x8 v; } u;
          u.w[0] = X0; u.w[1] = X1; u.w[2] = Y0; u.w[3] = Y1;
          pf[1][ks] = u.v;
        }
      }

      // O^T += V^T · P : A = V^T rows d, B = P cols q
      __builtin_amdgcn_s_setprio(1);
#pragma unroll
      for (int dt = 0; dt < 4; ++dt) {
        const int rv = dt * 32 + rl;
#pragma unroll
        for (int kvc = 0; kvc < 2; ++kvc)
#pragma unroll
          for (int ks = 0; ks < 2; ++ks) {
            const int cb = (kvc * 64 + ks * 32 + hi * 16) ^ swz;
            const bf16x8 vf = *reinterpret_cast<const bf16x8*>((const char*)Vb + rv * 128 + cb);
            ot[dt] = __builtin_amdgcn_mfma_f32_32x32x16_bf16(vf, pf[kvc][ks], ot[dt], 0, 0, 0);
          }
      }
      __builtin_amdgcn_s_setprio(0);
    }
  }

  // epilogue: O^T -> LDS transpose -> coalesced global store
  __syncthreads();   // all staging reads done; reuse smem
  const float inv = 1.0f / lsum;
  u16* ep = (u16*)smem + wid * (32 * 136);
#pragma unroll
  for (int dt = 0; dt < 4; ++dt)
#pragma unroll
    for (int r = 0; r < 16; ++r) {
      const int d = dt * 32 + (r & 3) + 8 * (r >> 2) + 4 * hi;
      ep[rl * 136 + d] = f2bf(ot[dt][r] * inv);
    }
  const int dh = hi * 64;
  const u16* srcp = (u16*)smem + wid * (32 * 136) + rl * 136 + dh;
  u16* gdst = Ow + ((size_t)(b * T_) + q0w + rl) * (NH * HD) + h * HD + dh;
#pragma unroll
  for (int c2 = 0; c2 < 8; ++c2)
    *reinterpret_cast<bf16x8*>(gdst + c2 * 8) =
        *reinterpret_cast<const bf16x8*>(srcp + c2 * 8);
}

// ---------------- host launch ----------------
extern "C" void kernel_launch(void* const* d_in, const int* in_sizes, int n_in,
                              void* d_out, int out_size, void* d_ws, size_t ws_size,
                              hipStream_t stream) {
  (void)in_sizes; (void)n_in; (void)out_size; (void)ws_size;
  const float* x    = (const float*)d_in[0];
  const float* cosT = (const float*)d_in[1];
  const float* sinT = (const float*)d_in[2];
  const int*   pos  = (const int*)d_in[3];
  const float* Wq   = (const float*)d_in[4];
  const float* Wk   = (const float*)d_in[5];
  const float* Wv   = (const float*)d_in[6];
  const float* Wo   = (const float*)d_in[7];
  const float* qw   = (const float*)d_in[8];
  const float* kw   = (const float*)d_in[9];
  float* out = (float*)d_out;

  char* ws = (char*)d_ws;
  u16* xb   = (u16*)(ws + 0);
  u16* Wqb  = (u16*)(ws + 16777216);
  u16* Wkb  = (u16*)(ws + 25165824);
  u16* Wvb  = (u16*)(ws + 29360128);
  u16* Wob  = (u16*)(ws + 33554432);
  u16* Qws  = (u16*)(ws + 41943040);
  u16* Kws  = (u16*)(ws + 58720256);
  u16* VTws = (u16*)(ws + 67108864);
  u16* Aws  = (u16*)(ws + 75497472);

  cvt_f32_bf16<<<8192, 256, 0, stream>>>(x,  xb,  2097152);
  cvt_f32_bf16<<<4096, 256, 0, stream>>>(Wq, Wqb, 1048576);
  cvt_f32_bf16<<<2048, 256, 0, stream>>>(Wk, Wkb, 524288);
  cvt_f32_bf16<<<2048, 256, 0, stream>>>(Wv, Wvb, 524288);
  cvt_f32_bf16<<<4096, 256, 0, stream>>>(Wo, Wob, 1048576);

  gemm_bt<0><<<dim3(16, 32), 256, 0, stream>>>(xb, Wqb, Qws, 4096, 2048, 2048);
  gemm_bt<0><<<dim3(8, 32),  256, 0, stream>>>(xb, Wkb, Kws, 4096, 1024, 2048);
  gemm_bt<1><<<dim3(8, 32),  256, 0, stream>>>(xb, Wvb, VTws, 4096, 1024, 2048);

  rms_rope<<<24576, 256, 0, stream>>>(Qws, Kws, cosT, sinT, pos, qw, kw);

  flash_attn2<<<512, 256, 0, stream>>>(Qws, Kws, VTws, Aws);

  gemm_bt<2><<<dim3(16, 32), 256, 0, stream>>>(Aws, Wob, out, 4096, 2048, 2048);
}

// Round 5
// 206.947 us; speedup vs baseline: 2.0903x; 1.5459x over previous
//
#include <hip/hip_runtime.h>
#include <stdint.h>
#include <stddef.h>

typedef unsigned short u16;
typedef __attribute__((ext_vector_type(4))) unsigned short u16x4;
typedef __attribute__((ext_vector_type(8))) short bf16x8;
typedef __attribute__((ext_vector_type(4))) float f32x4;
typedef __attribute__((ext_vector_type(16))) float f32x16;

// problem dims (fixed by setup_inputs)
#define B_   2
#define T_   2048
#define NH   16
#define NKV  8
#define HD   128

__device__ __forceinline__ u16 f2bf(float f) {
  union { float f; uint32_t u; } v; v.f = f;
  uint32_t u = v.u;
  u += 0x7FFFu + ((u >> 16) & 1u);   // round-to-nearest-even
  return (u16)(u >> 16);
}
__device__ __forceinline__ float bf2f(u16 h) {
  union { uint32_t u; float f; } v; v.u = ((uint32_t)h) << 16;
  return v.f;
}
__device__ __forceinline__ uint32_t cvt_pk_bf16(float lo, float hi) {
  uint32_t r;
  asm("v_cvt_pk_bf16_f32 %0, %1, %2" : "=v"(r) : "v"(lo), "v"(hi));
  return r;
}

// async global->LDS, 16B per lane. LDS dest must be linear in lane order.
__device__ __forceinline__ void gload_lds16(const void* g, void* l) {
  __builtin_amdgcn_global_load_lds(
      (__attribute__((address_space(1))) void*)g,
      (__attribute__((address_space(3))) void*)l, 16, 0, 0);
}

// ---------------- fp32 -> bf16 conversion ----------------
__global__ __launch_bounds__(256) void cvt_f32_bf16(const float* __restrict__ in,
                                                    u16* __restrict__ out, int n4) {
  int i = blockIdx.x * 256 + threadIdx.x;
  if (i >= n4) return;
  float4 v = reinterpret_cast<const float4*>(in)[i];
  u16x4 o;
  o.x = f2bf(v.x); o.y = f2bf(v.y); o.z = f2bf(v.z); o.w = f2bf(v.w);
  reinterpret_cast<u16x4*>(out)[i] = o;
}

// ---------------- GEMM v2: C = A[M,K]*B[N,K]^T, 2-phase dbuf + T2 swizzle ----
// 512 threads = 8 waves (2M x 4N). BK=64. Grid must be exactly 256 blocks.
// STORE=3: fused QKV epilogue (C0=Q rowmajor[.][2048], C1=K rowmajor[.][1024],
//          C2=V^T [B][1024][T]); STORE=2: f32 rowmajor C0.
template<int BM, int BN, int STORE>
__global__ __launch_bounds__(512, 2) void gemm2(const u16* __restrict__ A,
                                                const u16* __restrict__ Bm,
                                                void* __restrict__ C0,
                                                void* __restrict__ C1,
                                                void* __restrict__ C2,
                                                int M, int N, int K) {
  constexpr int FM  = BM / 32;      // A frags per wave (WM=2)
  constexpr int FN  = BN / 64;      // B frags per wave (WN=4)
  constexpr int ASZ = BM * 64;      // u16 per A tile
  constexpr int BSZ = BN * 64;
  __shared__ u16 lds[2 * (ASZ + BSZ)];

  const int tid  = threadIdx.x;
  const int lane = tid & 63;
  const int wid  = tid >> 6;
  const int lr   = lane & 15;
  const int lg   = lane >> 4;
  const int wm0 = (wid >> 2) * (BM / 2);
  const int wn0 = (wid & 3) * (BN / 4);

  // bijective XCD swizzle for exactly 256 workgroups (8 XCDs x 32)
  const int s  = ((blockIdx.x & 7) << 5) | (blockIdx.x >> 3);
  const int nx = N / BN;
  const int m0 = (s / nx) * BM;
  const int n0 = (s % nx) * BN;

  f32x4 acc[FM][FN];
#pragma unroll
  for (int i = 0; i < FM; ++i)
#pragma unroll
    for (int j = 0; j < FN; ++j) acc[i][j] = (f32x4){0.f, 0.f, 0.f, 0.f};

  auto stage = [&](int kt, int p) {
    const int k0 = kt << 6;
    u16* Ab = lds + p * (ASZ + BSZ);
    u16* Bb = Ab + ASZ;
#pragma unroll
    for (int it = 0; it < BM / 64; ++it) {     // A: BM*8 16B-chunks
      const int CI = it * 512 + tid;
      const int row = CI >> 3, c = CI & 7;     // 8 chunks per 128B row
      gload_lds16(A + (size_t)(m0 + row) * K + k0 + ((c ^ (row & 7)) << 3),
                  (char*)Ab + (size_t)CI * 16);
    }
#pragma unroll
    for (int it = 0; it < BN / 64; ++it) {
      const int CI = it * 512 + tid;
      const int row = CI >> 3, c = CI & 7;
      gload_lds16(Bm + (size_t)(n0 + row) * K + k0 + ((c ^ (row & 7)) << 3),
                  (char*)Bb + (size_t)CI * 16);
    }
  };

  const int nk = K >> 6;
  stage(0, 0);
  __syncthreads();                 // tile 0 landed
  int cur = 0;
  for (int kt = 0; kt < nk; ++kt) {
    if (kt + 1 < nk) stage(kt + 1, cur ^ 1);   // issue; drained by loop-end barrier
    const u16* Ab = lds + cur * (ASZ + BSZ);
    const u16* Bb = Ab + ASZ;
#pragma unroll
    for (int kk = 0; kk < 2; ++kk) {
      bf16x8 af[FM], bfr[FN];
#pragma unroll
      for (int mt = 0; mt < FM; ++mt) {
        const int ar = wm0 + mt * 16 + lr;
        af[mt] = *reinterpret_cast<const bf16x8*>(
            (const char*)Ab + ar * 128 + ((kk * 64 + lg * 16) ^ ((ar & 7) << 4)));
      }
#pragma unroll
      for (int nt = 0; nt < FN; ++nt) {
        const int br = wn0 + nt * 16 + lr;
        bfr[nt] = *reinterpret_cast<const bf16x8*>(
            (const char*)Bb + br * 128 + ((kk * 64 + lg * 16) ^ ((br & 7) << 4)));
      }
      __builtin_amdgcn_s_setprio(1);
#pragma unroll
      for (int mt = 0; mt < FM; ++mt)
#pragma unroll
        for (int nt = 0; nt < FN; ++nt)
          acc[mt][nt] = __builtin_amdgcn_mfma_f32_16x16x32_bf16(
              af[mt], bfr[nt], acc[mt][nt], 0, 0, 0);
      __builtin_amdgcn_s_setprio(0);
    }
    __syncthreads();               // drains next-tile staging; frees buf[cur]
    cur ^= 1;
  }

  if (STORE == 3) {
    u16* Qd = (u16*)C0; u16* Kd = (u16*)C1; u16* Vd = (u16*)C2;
    if (n0 < 2048) {
#pragma unroll
      for (int mt = 0; mt < FM; ++mt) {
        const int row = m0 + wm0 + mt * 16 + lg * 4;
#pragma unroll
        for (int nt = 0; nt < FN; ++nt) {
          const int col = n0 + wn0 + nt * 16 + lr;
#pragma unroll
          for (int r = 0; r < 4; ++r)
            Qd[(size_t)(row + r) * 2048 + col] = f2bf(acc[mt][nt][r]);
        }
      }
    } else if (n0 < 3072) {
#pragma unroll
      for (int mt = 0; mt < FM; ++mt) {
        const int row = m0 + wm0 + mt * 16 + lg * 4;
#pragma unroll
        for (int nt = 0; nt < FN; ++nt) {
          const int col = n0 + wn0 + nt * 16 + lr - 2048;
#pragma unroll
          for (int r = 0; r < 4; ++r)
            Kd[(size_t)(row + r) * 1024 + col] = f2bf(acc[mt][nt][r]);
        }
      }
    } else {   // V^T: Vd[(b*1024 + vc)*T_ + t]
#pragma unroll
      for (int mt = 0; mt < FM; ++mt) {
        const int row = m0 + wm0 + mt * 16 + lg * 4;
        const int b = row >> 11;
        const int t = row & (T_ - 1);
#pragma unroll
        for (int nt = 0; nt < FN; ++nt) {
          const int vc = n0 + wn0 + nt * 16 + lr - 3072;
          u16x4 v;
          v.x = f2bf(acc[mt][nt][0]); v.y = f2bf(acc[mt][nt][1]);
          v.z = f2bf(acc[mt][nt][2]); v.w = f2bf(acc[mt][nt][3]);
          *reinterpret_cast<u16x4*>(Vd + ((size_t)(b * 1024 + vc)) * T_ + t) = v;
        }
      }
    }
  } else {     // STORE == 2: f32 row-major
    float* C = (float*)C0;
#pragma unroll
    for (int mt = 0; mt < FM; ++mt) {
      const int row = m0 + wm0 + mt * 16 + lg * 4;
#pragma unroll
      for (int nt = 0; nt < FN; ++nt) {
        const int col = n0 + wn0 + nt * 16 + lr;
#pragma unroll
        for (int r = 0; r < 4; ++r)
          C[(size_t)(row + r) * N + col] = acc[mt][nt][r];
      }
    }
  }
}

// ---------------- per-head RMSNorm + RoPE on Q and K (in-place, bf16) -------
__global__ __launch_bounds__(256) void rms_rope(u16* __restrict__ Q, u16* __restrict__ Kb,
                                                const float* __restrict__ cosT,
                                                const float* __restrict__ sinT,
                                                const int* __restrict__ pos,
                                                const float* __restrict__ qw,
                                                const float* __restrict__ kw) {
  const int wave = blockIdx.x * 4 + (threadIdx.x >> 6);
  const int lane = threadIdx.x & 63;
  const int bt = wave & (B_ * T_ - 1);
  const int hh = wave >> 12;
  u16* ptr;
  const float* w;
  if (hh < NH) { ptr = Q + (size_t)bt * (NH * HD) + hh * HD; w = qw; }
  else         { ptr = Kb + (size_t)bt * (NKV * HD) + (hh - NH) * HD; w = kw; }
  const int p = pos[bt];

  float e0 = bf2f(ptr[lane]);
  float e1 = bf2f(ptr[lane + 64]);
  float ss = e0 * e0 + e1 * e1;
#pragma unroll
  for (int off = 1; off < 64; off <<= 1) ss += __shfl_xor(ss, off, 64);
  const float r = rsqrtf(ss * (1.0f / 128.0f) + 1e-6f);
  const float n0 = e0 * r * w[lane];
  const float n1 = e1 * r * w[lane + 64];
  const float c0 = cosT[(size_t)p * HD + lane], c1 = cosT[(size_t)p * HD + lane + 64];
  const float s0 = sinT[(size_t)p * HD + lane], s1 = sinT[(size_t)p * HD + lane + 64];
  ptr[lane]      = f2bf(n0 * c0 - n1 * s0);
  ptr[lane + 64] = f2bf(n1 * c1 + n0 * s1);
}

// ---------------- causal flash attention, swapped-QK^T 32x32, K/V dbuf ------
// 4 waves x 32 q-rows = 128 q/block; KVBLK=64; grid 512 blocks.
__global__ __launch_bounds__(256, 2) void flash_attn3(const u16* __restrict__ Qw,
                                                      const u16* __restrict__ Kw,
                                                      const u16* __restrict__ VTw,
                                                      u16* __restrict__ Ow) {
  __shared__ __align__(16) char smem[65536];   // 2 x (K 16KB + V 16KB); epi reuses base

  const int tid  = threadIdx.x;
  const int lane = tid & 63;
  const int wid  = tid >> 6;
  const int rl   = lane & 31;
  const int hi   = lane >> 5;
  const int blk  = blockIdx.x;
  const int qtr = blk >> 5;
  const int qt  = (blk < 256) ? (15 - qtr) : (qtr - 8);
  const int bh  = blk & 31;
  const int b   = bh >> 4, h = bh & 15, kvh = h >> 1;
  const int q0w = qt * 128 + wid * 32;
  const int qg  = q0w + rl;
  const int swz = (rl & 7) << 4;

  bf16x8 qf[8];
  {
    const u16* qp = Qw + ((size_t)(b * T_) + qg) * (NH * HD) + h * HD + hi * 8;
#pragma unroll
    for (int kd = 0; kd < 8; ++kd) qf[kd] = *reinterpret_cast<const bf16x8*>(qp + kd * 16);
  }

  f32x16 ot[4];
#pragma unroll
  for (int dt = 0; dt < 4; ++dt)
#pragma unroll
    for (int r = 0; r < 16; ++r) ot[dt][r] = 0.f;
  float m = -1e30f, lsum = 0.f;
  const float scale = 0.08838834764831845f;

  auto stageKV = [&](int kt, int p) {
    char* Kb = smem + p * 32768;
    char* Vb = Kb + 16384;
    {
      const int row = tid >> 4, ch = tid & 15;
#pragma unroll
      for (int it = 0; it < 4; ++it) {
        const int rr = it * 16 + row;
        const int scol = ((ch * 16) ^ ((rr & 7) << 4)) >> 1;
        gload_lds16(Kw + ((size_t)(b * T_) + kt * 64 + rr) * (NKV * HD) + kvh * HD + scol,
                    Kb + (it * 256 + tid) * 16);
      }
    }
    {
      const int row = tid >> 3, ch = tid & 7;
#pragma unroll
      for (int it = 0; it < 4; ++it) {
        const int rr = it * 32 + row;
        const int scol = ((ch * 16) ^ ((rr & 7) << 4)) >> 1;
        gload_lds16(VTw + ((size_t)((b * NKV + kvh) * HD) + rr) * T_ + kt * 64 + scol,
                    Vb + (it * 256 + tid) * 16);
      }
    }
  };

  const int nkt = 2 * qt + 2;
  stageKV(0, 0);
  __syncthreads();                       // tile 0 landed
  for (int kt = 0; kt < nkt; ++kt) {
    const int cur = kt & 1;
    if (kt + 1 < nkt) stageKV(kt + 1, cur ^ 1);   // in flight under compute

    if (64 * kt <= q0w + 31) {
      const u16* Kb = (const u16*)(smem + cur * 32768);
      const u16* Vb = (const u16*)(smem + cur * 32768 + 16384);

      f32x16 s0, s1;
#pragma unroll
      for (int r = 0; r < 16; ++r) { s0[r] = 0.f; s1[r] = 0.f; }
      __builtin_amdgcn_s_setprio(1);
#pragma unroll
      for (int kd = 0; kd < 8; ++kd) {
        const int cb = (kd * 32 + hi * 16) ^ swz;
        const bf16x8 k0 = *reinterpret_cast<const bf16x8*>((const char*)Kb + rl * 256 + cb);
        const bf16x8 k1 = *reinterpret_cast<const bf16x8*>((const char*)Kb + (32 + rl) * 256 + cb);
        s0 = __builtin_amdgcn_mfma_f32_32x32x16_bf16(k0, qf[kd], s0, 0, 0, 0);
        s1 = __builtin_amdgcn_mfma_f32_32x32x16_bf16(k1, qf[kd], s1, 0, 0, 0);
      }
      __builtin_amdgcn_s_setprio(0);

      const int kv0 = kt * 64;
      const bool maskT = (kv0 + 63 > q0w);
      float rm = -1e30f;
#pragma unroll
      for (int r = 0; r < 16; ++r) {
        const int cr = (r & 3) + 8 * (r >> 2) + 4 * hi;
        float a = s0[r] * scale, c = s1[r] * scale;
        if (maskT) {
          if (kv0 + cr > qg)      a = -1e30f;
          if (kv0 + 32 + cr > qg) c = -1e30f;
        }
        s0[r] = a; s1[r] = c;
        rm = fmaxf(rm, fmaxf(a, c));
      }
      rm = fmaxf(rm, __shfl_xor(rm, 32));
      const float mn = fmaxf(m, rm);
      const float al = __expf(m - mn);
      m = mn;
      float rs = 0.f;
#pragma unroll
      for (int r = 0; r < 16; ++r) {
        const float p0 = __expf(s0[r] - mn);
        const float p1 = __expf(s1[r] - mn);
        s0[r] = p0; s1[r] = p1;
        rs += p0 + p1;
      }
      rs += __shfl_xor(rs, 32);
      lsum = lsum * al + rs;
#pragma unroll
      for (int dt = 0; dt < 4; ++dt)
#pragma unroll
        for (int r = 0; r < 16; ++r) ot[dt][r] *= al;

      bf16x8 pf[2][2];
#pragma unroll
      for (int ks = 0; ks < 2; ++ks) {
        {
          uint32_t X0 = cvt_pk_bf16(s0[8 * ks + 0], s0[8 * ks + 1]);
          uint32_t X1 = cvt_pk_bf16(s0[8 * ks + 2], s0[8 * ks + 3]);
          uint32_t Y0 = cvt_pk_bf16(s0[8 * ks + 4], s0[8 * ks + 5]);
          uint32_t Y1 = cvt_pk_bf16(s0[8 * ks + 6], s0[8 * ks + 7]);
          asm volatile("v_permlane32_swap_b32 %0, %1" : "+v"(X0), "+v"(Y0));
          asm volatile("v_permlane32_swap_b32 %0, %1" : "+v"(X1), "+v"(Y1));
          union { uint32_t w[4]; bf16x8 v; } u;
          u.w[0] = X0; u.w[1] = X1; u.w[2] = Y0; u.w[3] = Y1;
          pf[0][ks] = u.v;
        }
        {
          uint32_t X0 = cvt_pk_bf16(s1[8 * ks + 0], s1[8 * ks + 1]);
          uint32_t X1 = cvt_pk_bf16(s1[8 * ks + 2], s1[8 * ks + 3]);
          uint32_t Y0 = cvt_pk_bf16(s1[8 * ks + 4], s1[8 * ks + 5]);
          uint32_t Y1 = cvt_pk_bf16(s1[8 * ks + 6], s1[8 * ks + 7]);
          asm volatile("v_permlane32_swap_b32 %0, %1" : "+v"(X0), "+v"(Y0));
          asm volatile("v_permlane32_swap_b32 %0, %1" : "+v"(X1), "+v"(Y1));
          union { uint32_t w[4]; bf16x8 v; } u;
          u.w[0] = X0; u.w[1] = X1; u.w[2] = Y0; u.w[3] = Y1;
          pf[1][ks] = u.v;
        }
      }

      __builtin_amdgcn_s_setprio(1);
#pragma unroll
      for (int dt = 0; dt < 4; ++dt) {
        const int rv = dt * 32 + rl;
#pragma unroll
        for (int kvc = 0; kvc < 2; ++kvc)
#pragma unroll
          for (int ks = 0; ks < 2; ++ks) {
            const int cb = (kvc * 64 + ks * 32 + hi * 16) ^ swz;
            const bf16x8 vf = *reinterpret_cast<const bf16x8*>((const char*)Vb + rv * 128 + cb);
            ot[dt] = __builtin_amdgcn_mfma_f32_32x32x16_bf16(vf, pf[kvc][ks], ot[dt], 0, 0, 0);
          }
      }
      __builtin_amdgcn_s_setprio(0);
    }
    __syncthreads();                    // drains next-tile staging; frees buf[cur]
  }

  // epilogue: O^T -> LDS transpose -> coalesced global store
  const float inv = 1.0f / lsum;
  u16* ep = (u16*)smem + wid * (32 * 136);
#pragma unroll
  for (int dt = 0; dt < 4; ++dt)
#pragma unroll
    for (int r = 0; r < 16; ++r) {
      const int d = dt * 32 + (r & 3) + 8 * (r >> 2) + 4 * hi;
      ep[rl * 136 + d] = f2bf(ot[dt][r] * inv);
    }
  const int dh = hi * 64;
  const u16* srcp = (u16*)smem + wid * (32 * 136) + rl * 136 + dh;
  u16* gdst = Ow + ((size_t)(b * T_) + q0w + rl) * (NH * HD) + h * HD + dh;
#pragma unroll
  for (int c2 = 0; c2 < 8; ++c2)
    *reinterpret_cast<bf16x8*>(gdst + c2 * 8) =
        *reinterpret_cast<const bf16x8*>(srcp + c2 * 8);
}

// ---------------- host launch ----------------
extern "C" void kernel_launch(void* const* d_in, const int* in_sizes, int n_in,
                              void* d_out, int out_size, void* d_ws, size_t ws_size,
                              hipStream_t stream) {
  (void)in_sizes; (void)n_in; (void)out_size; (void)ws_size;
  const float* x    = (const float*)d_in[0];
  const float* cosT = (const float*)d_in[1];
  const float* sinT = (const float*)d_in[2];
  const int*   pos  = (const int*)d_in[3];
  const float* Wq   = (const float*)d_in[4];
  const float* Wk   = (const float*)d_in[5];
  const float* Wv   = (const float*)d_in[6];
  const float* Wo   = (const float*)d_in[7];
  const float* qw   = (const float*)d_in[8];
  const float* kw   = (const float*)d_in[9];
  float* out = (float*)d_out;

  // workspace map (bytes). Wqb/Wkb/Wvb are contiguous -> one [4096][2048] W.
  char* ws = (char*)d_ws;
  u16* xb   = (u16*)(ws + 0);          // [4096][2048]
  u16* Wqb  = (u16*)(ws + 16777216);   // [2048][2048] (QKV part 1)
  u16* Wkb  = (u16*)(ws + 25165824);   // [1024][2048] (QKV part 2)
  u16* Wvb  = (u16*)(ws + 29360128);   // [1024][2048] (QKV part 3)
  u16* Wob  = (u16*)(ws + 33554432);   // [2048][2048]
  u16* Qws  = (u16*)(ws + 41943040);   // [4096][2048]
  u16* Kws  = (u16*)(ws + 58720256);   // [4096][1024]
  u16* VTws = (u16*)(ws + 67108864);   // [2][1024][2048]
  u16* Aws  = (u16*)(ws + 75497472);   // [4096][2048]

  cvt_f32_bf16<<<8192, 256, 0, stream>>>(x,  xb,  2097152);
  cvt_f32_bf16<<<4096, 256, 0, stream>>>(Wq, Wqb, 1048576);
  cvt_f32_bf16<<<2048, 256, 0, stream>>>(Wk, Wkb, 524288);
  cvt_f32_bf16<<<2048, 256, 0, stream>>>(Wv, Wvb, 524288);
  cvt_f32_bf16<<<4096, 256, 0, stream>>>(Wo, Wob, 1048576);

  // fused QKV projection: [4096,2048] x [4096,2048]^T, 256 blocks (1/CU)
  gemm2<256, 256, 3><<<256, 512, 0, stream>>>(xb, Wqb, Qws, Kws, VTws,
                                              4096, 4096, 2048);

  rms_rope<<<24576, 256, 0, stream>>>(Qws, Kws, cosT, sinT, pos, qw, kw);

  flash_attn3<<<512, 256, 0, stream>>>(Qws, Kws, VTws, Aws);

  // output projection: [4096,2048] x [2048,2048]^T -> f32, 256 blocks
  gemm2<128, 256, 2><<<256, 512, 0, stream>>>(Aws, Wob, out, nullptr, nullptr,
                                              4096, 2048, 2048);
}